// Round 1
// baseline (251.405 us; speedup 1.0000x reference)
//
#include <hip/hip_runtime.h>

// Problem shape (fixed by reference setup_inputs):
//   x, target: [B=8, C=256, H=128, W=128] float32, contiguous.
//   Reduction over (B,H,W) -> per-channel moments 1..5; loss = sum of 5
//   RMSE-sum terms over the C=256 moment vectors.
#define B_DIM 8
#define C_DIM 256
#define HW    16384                 // 128*128 floats, contiguous per (b,c)
#define NSLAB (B_DIM * C_DIM)       // 2048 slabs per tensor
#define N_PER_CHAN (B_DIM * HW)     // 131072 elements per channel

// Native clang vector for __builtin_nontemporal_load (HIP_vector_type is
// rejected by the builtin; ext_vector_type is accepted and still emits one
// global_load_dwordx4 with the nt bit set).
typedef float vfloat4 __attribute__((ext_vector_type(4)));

// ---------------------------------------------------------------------------
// Kernel 1 (R6 variant): nontemporal split-stream, 8-deep MLP.
// R1-R5 post-mortem: delivered BW pinned ~2.65-3.5 TB/s across interleaved /
// deep-batched / split-stream / nt shapes; CU-side resources all >=4x
// headroom (VALUBusy 12.7%, occupancy-insensitive). Kernel absent from
// rocprof top-5 (fills at 77us dominate) => kernel < 77us => >=3.5 TB/s.
// R6: double per-wave outstanding loads 4->8 dwordx4 (64->128 B/lane in
// flight) to halve issue->drain epochs on the L2-miss path. Element set and
// scalar accumulation order preserved exactly (bit-identical partials).
//
// Output layout: partial[row * NSLAB + slab], rows 0..4 = x power sums 1..5,
// rows 5..9 = t power sums 1..5.
// ---------------------------------------------------------------------------
__global__ __launch_bounds__(256) void pow_sums_kernel(
    const float* __restrict__ x,
    const float* __restrict__ t,
    float* __restrict__ partial)
{
    const int bid  = blockIdx.x;
    const int tid  = threadIdx.x;
    const int slab = bid >> 1;               // even/odd interleave
    const bool is_t = (bid & 1) != 0;        // wave-uniform
    const float* __restrict__ src = is_t ? t : x;
    const int row0 = is_t ? 5 : 0;

    const vfloat4* __restrict__ v = (const vfloat4*)(src + (size_t)slab * HW);

    float s[5];
#pragma unroll
    for (int k = 0; k < 5; ++k) s[k] = 0.0f;

    // Powers 1..5 of one element accumulated into s[0..4].
#define ACC1(vv)                          \
    {                                     \
        float _v  = (vv);                 \
        float _v2 = _v * _v;              \
        float _v3 = _v2 * _v;             \
        s[0] += _v;                       \
        s[1] += _v2;                      \
        s[2] += _v3;                      \
        s[3] += _v2 * _v2;                \
        s[4] += _v3 * _v2;                \
    }
#define ACC4(f) ACC1((f).x) ACC1((f).y) ACC1((f).z) ACC1((f).w)

    // 16 float4/thread, consumed in 2 batches of 8 independent nt loads
    // (128 B/lane in flight per batch). Accumulation order m = 0..15
    // ascending — identical to the 4x4 variant, partials bit-exact.
#pragma unroll
    for (int j = 0; j < 2; ++j) {
        const int base = tid + j * 2048;     // 8 * 256 threads
        vfloat4 a0 = __builtin_nontemporal_load(&v[base]);
        vfloat4 a1 = __builtin_nontemporal_load(&v[base + 256]);
        vfloat4 a2 = __builtin_nontemporal_load(&v[base + 512]);
        vfloat4 a3 = __builtin_nontemporal_load(&v[base + 768]);
        vfloat4 a4 = __builtin_nontemporal_load(&v[base + 1024]);
        vfloat4 a5 = __builtin_nontemporal_load(&v[base + 1280]);
        vfloat4 a6 = __builtin_nontemporal_load(&v[base + 1536]);
        vfloat4 a7 = __builtin_nontemporal_load(&v[base + 1792]);
        ACC4(a0) ACC4(a1) ACC4(a2) ACC4(a3)
        ACC4(a4) ACC4(a5) ACC4(a6) ACC4(a7)
    }
#undef ACC4
#undef ACC1

    // Wave-level butterfly reduce (wave = 64 lanes on gfx950).
#pragma unroll
    for (int off = 32; off > 0; off >>= 1) {
#pragma unroll
        for (int k = 0; k < 5; ++k) s[k] += __shfl_down(s[k], off, 64);
    }

    __shared__ float wsum[4][5];
    const int wave = tid >> 6;
    const int lane = tid & 63;
    if (lane == 0) {
#pragma unroll
        for (int k = 0; k < 5; ++k) wsum[wave][k] = s[k];
    }
    __syncthreads();

    if (tid < 5) {
        float vsum = wsum[0][tid] + wsum[1][tid] + wsum[2][tid] + wsum[3][tid];
        partial[(row0 + tid) * NSLAB + slab] = vsum;
    }
}

// ---------------------------------------------------------------------------
// Kernel 2: single block, 256 threads (thread c = channel c). Combines the
// 8 per-batch partials per channel in fp64, converts raw moments to central
// moments via binomial identities, reduces the 5 squared-diff sums across
// channels, writes the scalar loss.
// ---------------------------------------------------------------------------
__global__ __launch_bounds__(256) void finalize_kernel(
    const float* __restrict__ partial,
    float* __restrict__ out)
{
    const int c = threadIdx.x;  // channel

    double S[10];
#pragma unroll
    for (int k = 0; k < 10; ++k) S[k] = 0.0;

    for (int b = 0; b < B_DIM; ++b) {
        const int bid = b * C_DIM + c;  // coalesced across threads
#pragma unroll
        for (int k = 0; k < 10; ++k) S[k] += (double)partial[k * NSLAB + bid];
    }

    const double invN = 1.0 / (double)N_PER_CHAN;

    // x raw moments
    const double mux = S[0] * invN;
    const double M2x = S[1] * invN, M3x = S[2] * invN;
    const double M4x = S[3] * invN, M5x = S[4] * invN;
    // y raw moments
    const double muy = S[5] * invN;
    const double M2y = S[6] * invN, M3y = S[7] * invN;
    const double M4y = S[8] * invN, M5y = S[9] * invN;

    // Central moments via binomial expansion about the mean.
    const double mux2 = mux * mux, mux3 = mux2 * mux;
    const double c2x = M2x - mux2;
    const double c3x = M3x - 3.0 * mux * M2x + 2.0 * mux3;
    const double c4x = M4x - 4.0 * mux * M3x + 6.0 * mux2 * M2x - 3.0 * mux2 * mux2;
    const double c5x = M5x - 5.0 * mux * M4x + 10.0 * mux2 * M3x
                       - 10.0 * mux3 * M2x + 4.0 * mux3 * mux2;

    const double muy2 = muy * muy, muy3 = muy2 * muy;
    const double c2y = M2y - muy2;
    const double c3y = M3y - 3.0 * muy * M2y + 2.0 * muy3;
    const double c4y = M4y - 4.0 * muy * M3y + 6.0 * muy2 * M2y - 3.0 * muy2 * muy2;
    const double c5y = M5y - 5.0 * muy * M4y + 10.0 * muy2 * M3y
                       - 10.0 * muy3 * M2y + 4.0 * muy3 * muy2;

    const double d1 = mux - muy;
    const double d2 = c2x - c2y;
    const double d3 = c3x - c3y;
    const double d4 = c4x - c4y;
    const double d5 = c5x - c5y;

    __shared__ double red[5][C_DIM];
    red[0][c] = d1 * d1;
    red[1][c] = d2 * d2;
    red[2][c] = d3 * d3;
    red[3][c] = d4 * d4;
    red[4][c] = d5 * d5;
    __syncthreads();

    for (int st = 128; st > 0; st >>= 1) {
        if (c < st) {
#pragma unroll
            for (int k = 0; k < 5; ++k) red[k][c] += red[k][c + st];
        }
        __syncthreads();
    }

    if (c == 0) {
        out[0] = (float)(sqrt(red[0][0]) + sqrt(red[1][0]) + sqrt(red[2][0])
                         + sqrt(red[3][0]) + sqrt(red[4][0]));
    }
}

extern "C" void kernel_launch(void* const* d_in, const int* in_sizes, int n_in,
                              void* d_out, int out_size, void* d_ws, size_t ws_size,
                              hipStream_t stream) {
    const float* x = (const float*)d_in[0];       // x
    const float* t = (const float*)d_in[1];       // target
    float* out = (float*)d_out;                   // scalar fp32 loss
    float* partial = (float*)d_ws;                // 10 * 2048 floats = 80 KB

    pow_sums_kernel<<<2 * NSLAB, 256, 0, stream>>>(x, t, partial);
    finalize_kernel<<<1, 256, 0, stream>>>(partial, out);
}